// Round 4
// baseline (26.328 us; speedup 1.0000x reference)
//
#include <hip/hip_runtime.h>

#define NBINS 256
#define ROWS 96                    // b*c = 32*3
#define ROW_N (512 * 512)          // 262144 elements per row
#define BPR 16                     // blocks per row
#define CHUNK (ROW_N / BPR)        // 16384 elements per block
#define BLOCK 256
#define WAVES (BLOCK / 64)
#define BIN_W 0.99609375f          // (255-0)/256, exactly representable
#define RECIP_W 1.00392156862745098f  // fl(256/255)

__global__ void nh_zero_out(float* __restrict__ out) {
    out[blockIdx.x * NBINS + threadIdx.x] = 0.0f;
}

__global__ __launch_bounds__(BLOCK) void nh_hist(const float* __restrict__ x,
                                                 float* __restrict__ out) {
    __shared__ unsigned int lh[WAVES][NBINS + 1];   // +1 = trash for invalid
    const int tid = threadIdx.x;
    const int wave = tid >> 6;

    #pragma unroll
    for (int i = tid; i < WAVES * (NBINS + 1); i += BLOCK)
        ((unsigned int*)lh)[i] = 0u;
    __syncthreads();

    const int row = blockIdx.y;
    const float4* __restrict__ p =
        (const float4*)(x + (size_t)row * ROW_N + (size_t)blockIdx.x * CHUNK);

    #pragma unroll 4
    for (int i = tid; i < CHUNK / 4; i += BLOCK) {
        float4 v = p[i];
        float f[4] = {v.x, v.y, v.z, v.w};
        #pragma unroll
        for (int k = 0; k < 4; ++k) {
            float fv = f[k];
            // floor-estimate of fv / BIN_W via multiply; |err| <= 1 bin.
            float bf = truncf(fv * RECIP_W);
            // exact fixup: bf*BIN_W and (bf+1)*BIN_W are EXACT in fp32
            // (b <= 256, b*255 < 2^17), and t+BIN_W is an exact add, so the
            // compares compute true floor(fv/BIN_W).
            float t = bf * BIN_W;
            int b = (int)bf + (int)((t + BIN_W) <= fv) - (int)(t > fv);
            b = b > NBINS - 1 ? NBINS - 1 : b;   // also maps fv==255 -> 255
            // out-of-range (incl. NaN) -> trash slot, branchless
            bool valid = (fv >= 0.0f) && (fv <= 255.0f);
            int slot = valid ? b : NBINS;
            atomicAdd(&lh[wave][slot], 1u);
        }
    }
    __syncthreads();

    // cross-wave reduce, then ONE float atomic per (block, bin).
    // Exact: every partial is count*2^-18 (count <= 2^14); all intermediate
    // sums are multiples of 2^-18 with k <= 2^18 < 2^24 -> every fp32 add is
    // exact -> order-independent, bit-identical to the reference.
    unsigned int total = 0;
    #pragma unroll
    for (int w = 0; w < WAVES; ++w) total += lh[w][tid];
    atomicAdd(&out[row * NBINS + tid], (float)total * (1.0f / ROW_N));
}

extern "C" void kernel_launch(void* const* d_in, const int* in_sizes, int n_in,
                              void* d_out, int out_size, void* d_ws, size_t ws_size,
                              hipStream_t stream) {
    const float* x = (const float*)d_in[0];
    float* out = (float*)d_out;

    nh_zero_out<<<ROWS, NBINS, 0, stream>>>(out);

    dim3 grid(BPR, ROWS);
    nh_hist<<<grid, BLOCK, 0, stream>>>(x, out);
}